// Round 1
// baseline (110.211 us; speedup 1.0000x reference)
//
#include <hip/hip_runtime.h>
#include <math.h>

// Problem constants (from reference setup_inputs):
//   x: (B,S,G,D) f32,  norm_scale: (G,D) f32,  conv_kernel: (K, G*D) f32
//   out: (B,S,G,D) f32
// B=4, S=4096, G=4, D=1024, K=4, C=G*D=4096
constexpr int B = 4;
constexpr int S = 4096;
constexpr int G = 4;
constexpr int D = 1024;
constexpr int K = 4;
constexpr int C = G * D;
constexpr int CHUNK = 64;            // s-rows per block
constexpr float EPS = 1e-6f;

// Fused RMSNorm + causal depthwise conv1d (K=4) + SiLU.
// Block = (b, g, s-chunk). 256 threads; thread t owns channels d0=4t..4t+3.
// Per row: block-wide sum-of-squares reduce -> rsqrt -> normalize -> 4-row
// register sliding window -> 4-tap conv -> silu -> store.
__global__ __launch_bounds__(256)
void shortconv_fused_kernel(const float* __restrict__ x,
                            const float* __restrict__ scale,
                            const float* __restrict__ w,
                            float* __restrict__ out)
{
    __shared__ float red[2][4];      // double-buffered cross-wave partials

    const int tid  = threadIdx.x;
    const int lane = tid & 63;
    const int wid  = tid >> 6;
    const int bg   = blockIdx.y;     // 0..B*G-1
    const int b    = bg >> 2;        // bg / G   (G=4)
    const int g    = bg & 3;         // bg % G
    const int s0   = blockIdx.x * CHUNK;
    const int d0   = tid * 4;        // 256 threads * 4 = D

    const size_t srow = (size_t)G * D;                       // stride per s
    const size_t base = (size_t)b * S * srow + (size_t)g * D + d0;

    // Per-thread constants: scale + 4 conv taps for its 4 channels.
    const float4 sc = *(const float4*)(scale + g * D + d0);
    const float4 w0 = *(const float4*)(w + 0 * C + g * D + d0);
    const float4 w1 = *(const float4*)(w + 1 * C + g * D + d0);
    const float4 w2 = *(const float4*)(w + 2 * C + g * D + d0);
    const float4 w3 = *(const float4*)(w + 3 * C + g * D + d0);

    // Sliding window of normalized rows: win0=row s-3, win1=s-2, win2=s-1.
    float4 win0 = make_float4(0.f, 0.f, 0.f, 0.f);
    float4 win1 = make_float4(0.f, 0.f, 0.f, 0.f);
    float4 win2 = make_float4(0.f, 0.f, 0.f, 0.f);

    int s = s0 - (K - 1);
    float4 xv_next;
    if (s >= 0) xv_next = *(const float4*)(x + base + (size_t)s * srow);
    else        xv_next = make_float4(0.f, 0.f, 0.f, 0.f);

    const int s_end = s0 + CHUNK;
    for (; s < s_end; ++s) {
        float4 xv = xv_next;
        // Prefetch next row (independent of this row's reduce) to hide latency.
        const int sn = s + 1;
        if (sn < s_end) {
            xv_next = (sn >= 0) ? *(const float4*)(x + base + (size_t)sn * srow)
                                : make_float4(0.f, 0.f, 0.f, 0.f);
        }

        // Block-wide sum of squares over D=1024.
        float local = xv.x * xv.x + xv.y * xv.y + xv.z * xv.z + xv.w * xv.w;
        #pragma unroll
        for (int off = 32; off > 0; off >>= 1)
            local += __shfl_xor(local, off, 64);
        const int buf = s & 1;
        if (lane == 0) red[buf][wid] = local;
        __syncthreads();
        const float total = red[buf][0] + red[buf][1] + red[buf][2] + red[buf][3];
        const float invr  = rsqrtf(total * (1.0f / D) + EPS);

        // Normalize current row.
        float4 nv;
        nv.x = xv.x * invr * sc.x;
        nv.y = xv.y * invr * sc.y;
        nv.z = xv.z * invr * sc.z;
        nv.w = xv.w * invr * sc.w;

        if (s >= s0) {
            // y[s] = w0*xn[s-3] + w1*xn[s-2] + w2*xn[s-1] + w3*xn[s]
            float4 y;
            y.x = w0.x * win0.x + w1.x * win1.x + w2.x * win2.x + w3.x * nv.x;
            y.y = w0.y * win0.y + w1.y * win1.y + w2.y * win2.y + w3.y * nv.y;
            y.z = w0.z * win0.z + w1.z * win1.z + w2.z * win2.z + w3.z * nv.z;
            y.w = w0.w * win0.w + w1.w * win1.w + w2.w * win2.w + w3.w * nv.w;
            // SiLU: y * sigmoid(y)
            y.x = y.x / (1.f + __expf(-y.x));
            y.y = y.y / (1.f + __expf(-y.y));
            y.z = y.z / (1.f + __expf(-y.z));
            y.w = y.w / (1.f + __expf(-y.w));
            *(float4*)(out + base + (size_t)s * srow) = y;
        }

        // Shift window.
        win0 = win1;
        win1 = win2;
        win2 = nv;
    }
}

extern "C" void kernel_launch(void* const* d_in, const int* in_sizes, int n_in,
                              void* d_out, int out_size, void* d_ws, size_t ws_size,
                              hipStream_t stream) {
    const float* x     = (const float*)d_in[0];
    const float* scale = (const float*)d_in[1];
    const float* w     = (const float*)d_in[2];
    float* out         = (float*)d_out;

    dim3 grid(S / CHUNK, B * G);
    dim3 block(256);
    shortconv_fused_kernel<<<grid, block, 0, stream>>>(x, scale, w, out);
}

// Round 3
// 106.648 us; speedup vs baseline: 1.0334x; 1.0334x over previous
//
#include <hip/hip_runtime.h>
#include <math.h>

// x: (B,S,G,D) f32, norm_scale: (G,D) f32, conv_kernel: (K, G*D) f32
// out: (B,S,G,D) f32.  B=4, S=4096, G=4, D=1024, K=4, C=4096
constexpr int B = 4;
constexpr int S = 4096;
constexpr int G = 4;
constexpr int D = 1024;
constexpr int K = 4;
constexpr int C = G * D;
constexpr int CHUNK = 64;            // s-rows per block (outputs)
constexpr float EPS = 1e-6f;

typedef float v4f __attribute__((ext_vector_type(4)));  // native vec for nt-store

// Fused RMSNorm + causal depthwise conv1d (K=4) + SiLU.
// Block = (b, g, s-chunk). 256 threads; thread t owns channels 4t..4t+3.
// 2 rows per iteration, one barrier per pair (parity double-buffered LDS),
// 2-row-deep load prefetch. Window of 3 normalized rows in registers.
__global__ __launch_bounds__(256)
void shortconv_fused_kernel(const float* __restrict__ x,
                            const float* __restrict__ scale,
                            const float* __restrict__ w,
                            float* __restrict__ out)
{
    __shared__ float red[2][2][4];   // [parity][row-in-pair][wave]

    const int tid  = threadIdx.x;
    const int lane = tid & 63;
    const int wid  = tid >> 6;
    const int bg   = blockIdx.y;     // 0..B*G-1
    const int b    = bg >> 2;        // G=4
    const int g    = bg & 3;
    const int s0   = blockIdx.x * CHUNK;
    const int d0   = tid * 4;

    const size_t srow = (size_t)G * D;
    const size_t base = (size_t)b * S * srow + (size_t)g * D + d0;

    const float4 sc = *(const float4*)(scale + g * D + d0);
    const float4 w0 = *(const float4*)(w + 0 * C + g * D + d0);
    const float4 w1 = *(const float4*)(w + 1 * C + g * D + d0);
    const float4 w2 = *(const float4*)(w + 2 * C + g * D + d0);
    const float4 w3 = *(const float4*)(w + 3 * C + g * D + d0);

    const float4 zero = make_float4(0.f, 0.f, 0.f, 0.f);

    // Window: normalized rows s-3, s-2, s-1 (s = first row of current pair).
    float4 win0 = zero, win1 = zero, win2 = zero;

    // Pipeline starts at s0-4 (even); first pair's outputs are discarded
    // (s < s0) but its rows feed the window. Negative rows read as zero.
    int s = s0 - 4;
    float4 cur0 = (s     >= 0) ? *(const float4*)(x + base + (size_t)(s    ) * srow) : zero;
    float4 cur1 = (s + 1 >= 0) ? *(const float4*)(x + base + (size_t)(s + 1) * srow) : zero;

    const int s_end = s0 + CHUNK;
    for (; s < s_end; s += 2) {
        // Prefetch the next pair (2 rows deep).
        float4 nxt0 = zero, nxt1 = zero;
        if (s + 2 < s_end) {
            if (s + 2 >= 0) nxt0 = *(const float4*)(x + base + (size_t)(s + 2) * srow);
            if (s + 3 >= 0) nxt1 = *(const float4*)(x + base + (size_t)(s + 3) * srow);
        }

        // Sum of squares for both rows (interleaved shuffle chains for ILP).
        float l0 = cur0.x * cur0.x + cur0.y * cur0.y + cur0.z * cur0.z + cur0.w * cur0.w;
        float l1 = cur1.x * cur1.x + cur1.y * cur1.y + cur1.z * cur1.z + cur1.w * cur1.w;
        #pragma unroll
        for (int off = 32; off > 0; off >>= 1) {
            l0 += __shfl_xor(l0, off, 64);
            l1 += __shfl_xor(l1, off, 64);
        }
        const int buf = (s >> 1) & 1;
        if (lane == 0) {
            red[buf][0][wid] = l0;
            red[buf][1][wid] = l1;
        }
        __syncthreads();
        const float t0 = red[buf][0][0] + red[buf][0][1] + red[buf][0][2] + red[buf][0][3];
        const float t1 = red[buf][1][0] + red[buf][1][1] + red[buf][1][2] + red[buf][1][3];
        const float invr0 = rsqrtf(t0 * (1.0f / D) + EPS);
        const float invr1 = rsqrtf(t1 * (1.0f / D) + EPS);

        float4 nv0, nv1;
        nv0.x = cur0.x * invr0 * sc.x;  nv0.y = cur0.y * invr0 * sc.y;
        nv0.z = cur0.z * invr0 * sc.z;  nv0.w = cur0.w * invr0 * sc.w;
        nv1.x = cur1.x * invr1 * sc.x;  nv1.y = cur1.y * invr1 * sc.y;
        nv1.z = cur1.z * invr1 * sc.z;  nv1.w = cur1.w * invr1 * sc.w;

        if (s >= s0) {
            // y[s]   = w0*xn[s-3] + w1*xn[s-2] + w2*xn[s-1] + w3*xn[s]
            // y[s+1] = w0*xn[s-2] + w1*xn[s-1] + w2*xn[s]   + w3*xn[s+1]
            float4 y0, y1;
            y0.x = w0.x * win0.x + w1.x * win1.x + w2.x * win2.x + w3.x * nv0.x;
            y0.y = w0.y * win0.y + w1.y * win1.y + w2.y * win2.y + w3.y * nv0.y;
            y0.z = w0.z * win0.z + w1.z * win1.z + w2.z * win2.z + w3.z * nv0.z;
            y0.w = w0.w * win0.w + w1.w * win1.w + w2.w * win2.w + w3.w * nv0.w;
            y1.x = w0.x * win1.x + w1.x * win2.x + w2.x * nv0.x + w3.x * nv1.x;
            y1.y = w0.y * win1.y + w1.y * win2.y + w2.y * nv0.y + w3.y * nv1.y;
            y1.z = w0.z * win1.z + w1.z * win2.z + w2.z * nv0.z + w3.z * nv1.z;
            y1.w = w0.w * win1.w + w1.w * win2.w + w2.w * nv0.w + w3.w * nv1.w;
            // SiLU via fast rcp: y * 1/(1+exp(-y))
            y0.x *= __builtin_amdgcn_rcpf(1.f + __expf(-y0.x));
            y0.y *= __builtin_amdgcn_rcpf(1.f + __expf(-y0.y));
            y0.z *= __builtin_amdgcn_rcpf(1.f + __expf(-y0.z));
            y0.w *= __builtin_amdgcn_rcpf(1.f + __expf(-y0.w));
            y1.x *= __builtin_amdgcn_rcpf(1.f + __expf(-y1.x));
            y1.y *= __builtin_amdgcn_rcpf(1.f + __expf(-y1.y));
            y1.z *= __builtin_amdgcn_rcpf(1.f + __expf(-y1.z));
            y1.w *= __builtin_amdgcn_rcpf(1.f + __expf(-y1.w));
            v4f yv0 = { y0.x, y0.y, y0.z, y0.w };
            v4f yv1 = { y1.x, y1.y, y1.z, y1.w };
            __builtin_nontemporal_store(yv0, (v4f*)(out + base + (size_t)(s    ) * srow));
            __builtin_nontemporal_store(yv1, (v4f*)(out + base + (size_t)(s + 1) * srow));
        }

        // Shift window by 2 rows.
        win0 = win2;
        win1 = nv0;
        win2 = nv1;
        cur0 = nxt0;
        cur1 = nxt1;
    }
}

extern "C" void kernel_launch(void* const* d_in, const int* in_sizes, int n_in,
                              void* d_out, int out_size, void* d_ws, size_t ws_size,
                              hipStream_t stream) {
    const float* x     = (const float*)d_in[0];
    const float* scale = (const float*)d_in[1];
    const float* w     = (const float*)d_in[2];
    float* out         = (float*)d_out;

    dim3 grid(S / CHUNK, B * G);
    dim3 block(256);
    shortconv_fused_kernel<<<grid, block, 0, stream>>>(x, scale, w, out);
}